// Round 6
// baseline (425.051 us; speedup 1.0000x reference)
//
#include <hip/hip_runtime.h>

#define B_ 2
#define S_ 2048
#define D_ 2048
#define H_ 16
#define HD_ 128
#define WIN_ 1024
#define M_ (B_*S_)      // 4096 rows (b*S+s)
#define N_ (H_*HD_)     // 2048
#define SCALE_ 0.08838834764831845f
#define CSHIFT_ 11.5f   // fixed softmax shift: scores*SCALE <= ~11.36 (rows RMS-normed)

typedef unsigned short u16;
typedef __attribute__((ext_vector_type(8))) short short8;   // 8 bf16 (4 VGPRs)
typedef __attribute__((ext_vector_type(4))) float f32x4;    // MFMA C/D

__device__ __forceinline__ float b2f(u16 u) {
    union { unsigned int i; float f; } x; x.i = ((unsigned int)u) << 16; return x.f;
}
__device__ __forceinline__ u16 f2b(float f) {  // RNE
    union { float f; unsigned int i; } x; x.f = f;
    unsigned int u = x.i;
    return (u16)((u + 0x7fffu + ((u >> 16) & 1u)) >> 16);
}

// async global->LDS, 16B per lane; lds dest wave-uniform base (HW adds lane*16)
__device__ __forceinline__ void async_ld16(const u16* g, u16* l) {
    __builtin_amdgcn_global_load_lds(
        (const __attribute__((address_space(1))) unsigned int*)g,
        (__attribute__((address_space(3))) unsigned int*)l, 16, 0, 0);
}

// ---------------------------------------------------------------- prep: 4x transpose + hs cast, one launch
// z in 0..3: transpose+cast W[z] (2048x2048 fp32 -> bf16 N-major)
// z == 4:   cast hs fp32 -> bf16 (8M elems)
__global__ __launch_bounds__(256) void prep_kernel(const float* __restrict__ hs, u16* __restrict__ hsb,
                                                   const float* __restrict__ W0, const float* __restrict__ W1,
                                                   const float* __restrict__ W2, const float* __restrict__ W3,
                                                   u16* __restrict__ O0, u16* __restrict__ O1,
                                                   u16* __restrict__ O2, u16* __restrict__ O3) {
    if (blockIdx.z == 4) {
        const int linear = blockIdx.y * 64 + blockIdx.x;          // 0..4095
        int i = linear * 256 + threadIdx.x;                       // 0..1048575
#pragma unroll
        for (int rep = 0; rep < 2; ++rep, i += 1048576) {
            float4 v = ((const float4*)hs)[i];
            ushort4 o;
            o.x = f2b(v.x); o.y = f2b(v.y); o.z = f2b(v.z); o.w = f2b(v.w);
            ((ushort4*)hsb)[i] = o;
        }
        return;
    }
    __shared__ float tile[32][33];
    const float* in; u16* out;
    switch (blockIdx.z) {
        case 0: in = W0; out = O0; break;
        case 1: in = W1; out = O1; break;
        case 2: in = W2; out = O2; break;
        default: in = W3; out = O3; break;
    }
    const int C = 2048, R = 2048;
    int c0 = blockIdx.x * 32, r0 = blockIdx.y * 32;
    int tx = threadIdx.x & 31, ty = threadIdx.x >> 5;  // 32 x 8
#pragma unroll
    for (int rr = ty; rr < 32; rr += 8)
        tile[rr][tx] = in[(long)(r0 + rr) * C + c0 + tx];
    __syncthreads();
#pragma unroll
    for (int cc = ty; cc < 32; cc += 8)
        out[(long)(c0 + cc) * R + r0 + tx] = f2b(tile[tx][cc]);
}

// ---------------------------------------------------------------- merged QKV GEMM
// A (4096 x 2048) bf16, Bt3 (6144 x 2048) bf16 = [Wq^T; Wk^T; Wv^T].
// 128x128 tile, BK=32, global_load_lds w16, XOR-chunk-swizzled LDS (conflict-free, verified R5).
// seg0/1 -> Q/K bf16 row-major; seg2 -> V transposed to (B,H,HD,S).
// Lean epilogue on purpose: fused norm (R4) cost VGPR 76->128, occ 31->21%, -28% perf.
__global__ __launch_bounds__(256) void gemm_qkv_kernel(const u16* __restrict__ A,
                                                       const u16* __restrict__ Bt3,
                                                       u16* __restrict__ Qb,
                                                       u16* __restrict__ Kb,
                                                       u16* __restrict__ Vtb) {
    constexpr int Kk = 2048;
    __shared__ u16 As[128 * 32];
    __shared__ u16 Bs[128 * 32];

    const int tid  = threadIdx.x;
    const int m0   = blockIdx.y * 128, n0 = blockIdx.x * 128;
    const int wid  = tid >> 6, lane = tid & 63;
    const int wm   = (wid >> 1) * 64, wn = (wid & 1) * 64;
    const int quad = lane >> 4, lrow = lane & 15;
    const int lr4  = lane >> 2, lc4 = lane & 3;
    const int swz  = (lr4 >> 1) & 3;           // staging-side swizzle
    const int rsw  = (lrow >> 1) & 3;          // read-side swizzle

    f32x4 acc[4][4];
#pragma unroll
    for (int a = 0; a < 4; ++a)
#pragma unroll
        for (int b = 0; b < 4; ++b) acc[a][b] = (f32x4)0.0f;

    for (int k0 = 0; k0 < Kk; k0 += 32) {
        __syncthreads();
#pragma unroll
        for (int it = 0; it < 2; ++it) {
            const int ra = (wid + 4 * it) * 16;
            async_ld16(&A  [(long)(m0 + ra + lr4) * Kk + k0 + ((lc4 ^ swz) * 8)], &As[ra * 32]);
            async_ld16(&Bt3[(long)(n0 + ra + lr4) * Kk + k0 + ((lc4 ^ swz) * 8)], &Bs[ra * 32]);
        }
        __syncthreads();

        short8 af[4], bf[4];
#pragma unroll
        for (int t = 0; t < 4; ++t)
            af[t] = *(const short8*)&As[(wm + t * 16 + lrow) * 32 + ((quad ^ rsw) * 8)];
#pragma unroll
        for (int t = 0; t < 4; ++t)
            bf[t] = *(const short8*)&Bs[(wn + t * 16 + lrow) * 32 + ((quad ^ rsw) * 8)];
#pragma unroll
        for (int tm = 0; tm < 4; ++tm)
#pragma unroll
            for (int tn = 0; tn < 4; ++tn)
                acc[tm][tn] = __builtin_amdgcn_mfma_f32_16x16x32_bf16(
                    af[tm], bf[tn], acc[tm][tn], 0, 0, 0);
    }

    const int seg = n0 >> 11;  // block-uniform: 0=Q, 1=K, 2=V
#pragma unroll
    for (int tm = 0; tm < 4; ++tm)
#pragma unroll
        for (int tn = 0; tn < 4; ++tn) {
            const int colg = (n0 & 2047) + wn + tn * 16 + lrow;
            const int rowb = m0 + wm + tm * 16 + quad * 4;
            if (seg == 2) {
                const int b = rowb >> 11, s = rowb & (S_ - 1);
                const int h = colg >> 7, d = colg & (HD_ - 1);
                ushort4 pk;
                pk.x = f2b(acc[tm][tn][0]); pk.y = f2b(acc[tm][tn][1]);
                pk.z = f2b(acc[tm][tn][2]); pk.w = f2b(acc[tm][tn][3]);
                *(ushort4*)&Vtb[((long)((b * H_ + h) * HD_ + d)) * S_ + s] = pk;
            } else {
                u16* dst = (seg == 0) ? Qb : Kb;
#pragma unroll
                for (int r = 0; r < 4; ++r)
                    dst[(long)(rowb + r) * N_ + colg] = f2b(acc[tm][tn][r]);
            }
        }
}

// ---------------------------------------------------------------- final projection GEMM (fp32 out), swizzled LDS
__global__ __launch_bounds__(256) void gemm_out_kernel(const u16* __restrict__ A,
                                                       const u16* __restrict__ Bt,
                                                       float* __restrict__ C) {
    constexpr int Kk = 2048, Nn = 2048;
    __shared__ u16 As[128 * 32];
    __shared__ u16 Bs[128 * 32];

    const int tid  = threadIdx.x;
    const int m0   = blockIdx.y * 128, n0 = blockIdx.x * 128;
    const int wid  = tid >> 6, lane = tid & 63;
    const int wm   = (wid >> 1) * 64, wn = (wid & 1) * 64;
    const int quad = lane >> 4, lrow = lane & 15;
    const int lr4  = lane >> 2, lc4 = lane & 3;
    const int swz  = (lr4 >> 1) & 3;
    const int rsw  = (lrow >> 1) & 3;

    f32x4 acc[4][4];
#pragma unroll
    for (int a = 0; a < 4; ++a)
#pragma unroll
        for (int b = 0; b < 4; ++b) acc[a][b] = (f32x4)0.0f;

    for (int k0 = 0; k0 < Kk; k0 += 32) {
        __syncthreads();
#pragma unroll
        for (int it = 0; it < 2; ++it) {
            const int ra = (wid + 4 * it) * 16;
            async_ld16(&A [(long)(m0 + ra + lr4) * Kk + k0 + ((lc4 ^ swz) * 8)], &As[ra * 32]);
            async_ld16(&Bt[(long)(n0 + ra + lr4) * Kk + k0 + ((lc4 ^ swz) * 8)], &Bs[ra * 32]);
        }
        __syncthreads();

        short8 af[4], bf[4];
#pragma unroll
        for (int t = 0; t < 4; ++t)
            af[t] = *(const short8*)&As[(wm + t * 16 + lrow) * 32 + ((quad ^ rsw) * 8)];
#pragma unroll
        for (int t = 0; t < 4; ++t)
            bf[t] = *(const short8*)&Bs[(wn + t * 16 + lrow) * 32 + ((quad ^ rsw) * 8)];
#pragma unroll
        for (int tm = 0; tm < 4; ++tm)
#pragma unroll
            for (int tn = 0; tn < 4; ++tn)
                acc[tm][tn] = __builtin_amdgcn_mfma_f32_16x16x32_bf16(
                    af[tm], bf[tn], acc[tm][tn], 0, 0, 0);
    }

#pragma unroll
    for (int tm = 0; tm < 4; ++tm)
#pragma unroll
        for (int tn = 0; tn < 4; ++tn) {
            const int col  = n0 + wn + tn * 16 + lrow;
            const int rowb = m0 + wm + tm * 16 + quad * 4;
#pragma unroll
            for (int r = 0; r < 4; ++r)
                C[(long)(rowb + r) * Nn + col] = acc[tm][tn][r];
        }
}

// ---------------------------------------------------------------- RMSNorm + RoPE, in place; grid.y selects Q/K
__global__ __launch_bounds__(256) void norm_rope_kernel(u16* __restrict__ Q, u16* __restrict__ Kb,
                                                        const float* __restrict__ qsc,
                                                        const float* __restrict__ ksc,
                                                        const float* __restrict__ cosp,
                                                        const float* __restrict__ sinp) {
    u16* X = blockIdx.y ? Kb : Q;
    const float* scale = blockIdx.y ? ksc : qsc;
    int wid = threadIdx.x >> 6, lane = threadIdx.x & 63;
    int row = blockIdx.x * 4 + wid;     // (b*S+s)*H + h
    int bs  = row >> 4;                 // /H_
    long off = (long)row * HD_;
    float x1 = b2f(X[off + lane]);
    float x2 = b2f(X[off + lane + 64]);
    float ss = x1 * x1 + x2 * x2;
#pragma unroll
    for (int o = 1; o < 64; o <<= 1) ss += __shfl_xor(ss, o);
    float inv = rsqrtf(ss * (1.0f / HD_) + 1e-6f);
    long cb = (long)(bs & (S_ - 1)) * HD_;
    float c1 = cosp[cb + lane],      s1 = sinp[cb + lane];
    float c2 = cosp[cb + lane + 64], s2 = sinp[cb + lane + 64];
    float n1 = scale[lane] * x1 * inv;
    float n2 = scale[lane + 64] * x2 * inv;
    X[off + lane]      = f2b(n1 * c1 - n2 * s1);
    X[off + lane + 64] = f2b(n2 * c2 + n1 * s2);
}

// ---------------------------------------------------------------- MFMA flash attention
// Block: (b,h) x 64 queries; 4 waves x 16 q rows; 64-key tiles. Grid 1024 = 1.33x the
// 3-blocks/CU capacity -> FIFO self-balancing of the 2..17-tile work spread (R5 lesson:
// grid==slots at 512 pinned the dispatch to the unluckiest CU).
// Fixed-shift softmax. K/V staged via global_load_lds with XOR chunk swizzle.
__global__ __launch_bounds__(256) void fattn_kernel(const u16* __restrict__ Q,
                                                    const u16* __restrict__ K,
                                                    const u16* __restrict__ Vt,
                                                    u16* __restrict__ O) {
    __shared__ u16 Ks[64 * 128];      // [key][d-chunk swizzled], 256B rows (16 KB)
    __shared__ u16 Vs[128 * 64];      // [d][key-chunk swizzled], 128B rows (16 KB)
    __shared__ u16 Ps[4][16 * 72];    // per-wave [q][key], stride 144B (9 KB)

    const int tid  = threadIdx.x;
    const int wid  = tid >> 6, lane = tid & 63;
    const int quad = lane >> 4, lrow = lane & 15;
    const int qb = 31 - (blockIdx.x & 31);          // heavy blocks first
    const int h  = (blockIdx.x >> 5) & (H_ - 1);
    const int b  = blockIdx.x >> 9;
    const int q0  = qb * 64;
    const int q0w = q0 + wid * 16;

    // Q A-frags: lane holds Q[q=q0w+lrow][d = c*32 + quad*8 .. +7]
    short8 qf[4];
    const long qrow = ((long)(b * S_ + q0w + lrow) * H_ + h) * HD_;
#pragma unroll
    for (int c = 0; c < 4; ++c)
        qf[c] = *(const short8*)&Q[qrow + c * 32 + quad * 8];

    float l_r[4] = {0.f, 0.f, 0.f, 0.f};
    f32x4 oacc[8];
#pragma unroll
    for (int t = 0; t < 8; ++t) oacc[t] = (f32x4)0.0f;

    const int ktlo = (q0 - WIN_ > 0) ? (q0 - WIN_) : 0;   // 64-aligned
    const long kgbase = ((long)b * S_ * H_ + h) * HD_;
    const long vgbase = ((long)(b * H_ + h) * HD_) * S_;
    const int lxor = lrow & 7;

    for (int kt0 = ktlo; kt0 < q0 + 64; kt0 += 64) {
        __syncthreads();  // previous tile's LDS reads done
        // K tile: 64 rows x 256B; 4 issues/wave, 4 rows each
#pragma unroll
        for (int it = 0; it < 4; ++it) {
            const int rb = (wid * 4 + it) * 4;
            const int row = rb + (lane >> 4);
            const int cg = (lane & 15) ^ (row & 7);
            async_ld16(&K[kgbase + (long)(kt0 + row) * (H_ * HD_) + cg * 8], &Ks[rb * 128]);
        }
        // V tile: 128 d-rows x 128B; 4 issues/wave, 8 rows each
#pragma unroll
        for (int it = 0; it < 4; ++it) {
            const int db = (wid * 4 + it) * 8;
            const int d = db + (lane >> 3);
            const int cg = (lane & 7) ^ (d & 7);
            async_ld16(&Vt[vgbase + (long)d * S_ + kt0 + cg * 8], &Vs[db * 64]);
        }
        __syncthreads();  // drains vmcnt

        const bool active = (kt0 <= q0w + 15) && (kt0 + 63 >= q0w - WIN_);
        if (active) {
            f32x4 cs[4];
#pragma unroll
            for (int t = 0; t < 4; ++t) {
                cs[t] = (f32x4)0.0f;
                const int krow = (t * 16 + lrow) * 128;
#pragma unroll
                for (int c = 0; c < 4; ++c) {
                    short8 kf = *(const short8*)&Ks[krow + (((c * 4 + quad) ^ lxor) * 8)];
                    cs[t] = __builtin_amdgcn_mfma_f32_16x16x32_bf16(qf[c], kf, cs[t], 0, 0, 0);
                }
            }

            const bool full = (kt0 + 63 <= q0w) && (kt0 >= q0w + 15 - WIN_);
            if (!full) {
#pragma unroll
                for (int t = 0; t < 4; ++t) {
                    const int jc = kt0 + t * 16 + lrow;
#pragma unroll
                    for (int r = 0; r < 4; ++r) {
                        const int i = q0w + quad * 4 + r;
                        if (jc > i || jc < i - WIN_) cs[t][r] = -1e30f;
                    }
                }
            }

#pragma unroll
            for (int t = 0; t < 4; ++t)
#pragma unroll
                for (int r = 0; r < 4; ++r) {
                    float p = __expf(fmaf(cs[t][r], SCALE_, -CSHIFT_));
                    l_r[r] += p;
                    Ps[wid][(quad * 4 + r) * 72 + t * 16 + lrow] = f2b(p);
                }

            short8 pf0 = *(const short8*)&Ps[wid][lrow * 72 + quad * 8];
            short8 pf1 = *(const short8*)&Ps[wid][lrow * 72 + 32 + quad * 8];
#pragma unroll
            for (int t = 0; t < 8; ++t) {
                const int vrow = (t * 16 + lrow) * 64;
                short8 vf0 = *(const short8*)&Vs[vrow + ((quad ^ lxor) * 8)];
                short8 vf1 = *(const short8*)&Vs[vrow + (((quad + 4) ^ lxor) * 8)];
                oacc[t] = __builtin_amdgcn_mfma_f32_16x16x32_bf16(pf0, vf0, oacc[t], 0, 0, 0);
                oacc[t] = __builtin_amdgcn_mfma_f32_16x16x32_bf16(pf1, vf1, oacc[t], 0, 0, 0);
            }
        }
    }

    float inv[4];
#pragma unroll
    for (int r = 0; r < 4; ++r) {
        float v = l_r[r];
#pragma unroll
        for (int o = 1; o < 16; o <<= 1) v += __shfl_xor(v, o);
        inv[r] = 1.0f / v;
    }

#pragma unroll
    for (int t = 0; t < 8; ++t) {
        const int d = t * 16 + lrow;
#pragma unroll
        for (int r = 0; r < 4; ++r) {
            const int q = q0w + quad * 4 + r;
            O[(long)(b * S_ + q) * N_ + h * HD_ + d] = f2b(oacc[t][r] * inv[r]);
        }
    }
}

// ----------------------------------------------------------------
extern "C" void kernel_launch(void* const* d_in, const int* in_sizes, int n_in,
                              void* d_out, int out_size, void* d_ws, size_t ws_size,
                              hipStream_t stream) {
    const float* hs   = (const float*)d_in[0];
    const float* cosp = (const float*)d_in[1];
    const float* sinp = (const float*)d_in[2];
    const float* Wq   = (const float*)d_in[3];
    const float* Wk   = (const float*)d_in[4];
    const float* Wv   = (const float*)d_in[5];
    const float* Wo   = (const float*)d_in[6];
    const float* qsc  = (const float*)d_in[7];
    const float* ksc  = (const float*)d_in[8];
    float* out = (float*)d_out;

    char* ws = (char*)d_ws;
    const size_t MD = (size_t)M_ * D_;  // 8M elems
    const size_t WN = (size_t)D_ * N_;  // 4M elems
    u16* hsb = (u16*)ws;                 // reused as attention output later
    u16* Wqt = (u16*)(ws + MD * 2);      // Wqt/Wkt/Wvt contiguous -> one 6144-row B
    u16* Wkt = Wqt + WN;
    u16* Wvt = Wkt + WN;
    u16* Wot = Wvt + WN;
    u16* Qb  = Wot + WN;
    u16* Kb  = Qb + MD;
    u16* Vtb = Kb + MD;                  // V transposed (B,H,HD,S)
    u16* Ab  = hsb;

    dim3 gp(64, 64, 5);
    prep_kernel<<<gp, 256, 0, stream>>>(hs, hsb, Wq, Wk, Wv, Wo, Wqt, Wkt, Wvt, Wot);

    dim3 gqkv(48, 32);  // N=6144
    gemm_qkv_kernel<<<gqkv, 256, 0, stream>>>(hsb, Wqt, Qb, Kb, Vtb);

    dim3 gn(B_ * S_ * H_ / 4, 2);
    norm_rope_kernel<<<gn, 256, 0, stream>>>(Qb, Kb, qsc, ksc, cosp, sinp);

    fattn_kernel<<<B_ * H_ * (S_ / 64), 256, 0, stream>>>(Qb, Kb, Vtb, Ab);

    dim3 gout(16, 32);
    gemm_out_kernel<<<gout, 256, 0, stream>>>(Ab, Wot, out);
}

// Round 7
// 390.917 us; speedup vs baseline: 1.0873x; 1.0873x over previous
//
#include <hip/hip_runtime.h>

#define B_ 2
#define S_ 2048
#define D_ 2048
#define H_ 16
#define HD_ 128
#define WIN_ 1024
#define M_ (B_*S_)      // 4096 rows (b*S+s)
#define N_ (H_*HD_)     // 2048
#define SCALE_ 0.08838834764831845f
#define CSHIFT_ 11.5f   // fixed softmax shift: scores*SCALE <= ~11.36 (rows RMS-normed)

typedef unsigned short u16;
typedef __attribute__((ext_vector_type(8))) short short8;   // 8 bf16 (4 VGPRs)
typedef __attribute__((ext_vector_type(4))) float f32x4;    // MFMA C/D

__device__ __forceinline__ float b2f(u16 u) {
    union { unsigned int i; float f; } x; x.i = ((unsigned int)u) << 16; return x.f;
}
__device__ __forceinline__ u16 f2b(float f) {  // RNE
    union { float f; unsigned int i; } x; x.f = f;
    unsigned int u = x.i;
    return (u16)((u + 0x7fffu + ((u >> 16) & 1u)) >> 16);
}

// async global->LDS, 16B per lane; lds dest wave-uniform base (HW adds lane*16)
__device__ __forceinline__ void async_ld16(const u16* g, u16* l) {
    __builtin_amdgcn_global_load_lds(
        (const __attribute__((address_space(1))) unsigned int*)g,
        (__attribute__((address_space(3))) unsigned int*)l, 16, 0, 0);
}

// ---------------------------------------------------------------- prep: 4x transpose + hs cast, one launch
// z in 0..3: transpose+cast W[z] (2048x2048 fp32 -> bf16 N-major)
// z == 4:   cast hs fp32 -> bf16 (8M elems)
__global__ __launch_bounds__(256) void prep_kernel(const float* __restrict__ hs, u16* __restrict__ hsb,
                                                   const float* __restrict__ W0, const float* __restrict__ W1,
                                                   const float* __restrict__ W2, const float* __restrict__ W3,
                                                   u16* __restrict__ O0, u16* __restrict__ O1,
                                                   u16* __restrict__ O2, u16* __restrict__ O3) {
    if (blockIdx.z == 4) {
        const int linear = blockIdx.y * 64 + blockIdx.x;          // 0..4095
        int i = linear * 256 + threadIdx.x;                       // 0..1048575
#pragma unroll
        for (int rep = 0; rep < 2; ++rep, i += 1048576) {
            float4 v = ((const float4*)hs)[i];
            ushort4 o;
            o.x = f2b(v.x); o.y = f2b(v.y); o.z = f2b(v.z); o.w = f2b(v.w);
            ((ushort4*)hsb)[i] = o;
        }
        return;
    }
    __shared__ float tile[32][33];
    const float* in; u16* out;
    switch (blockIdx.z) {
        case 0: in = W0; out = O0; break;
        case 1: in = W1; out = O1; break;
        case 2: in = W2; out = O2; break;
        default: in = W3; out = O3; break;
    }
    const int C = 2048, R = 2048;
    int c0 = blockIdx.x * 32, r0 = blockIdx.y * 32;
    int tx = threadIdx.x & 31, ty = threadIdx.x >> 5;  // 32 x 8
#pragma unroll
    for (int rr = ty; rr < 32; rr += 8)
        tile[rr][tx] = in[(long)(r0 + rr) * C + c0 + tx];
    __syncthreads();
#pragma unroll
    for (int cc = ty; cc < 32; cc += 8)
        out[(long)(c0 + cc) * R + r0 + tx] = f2b(tile[tx][cc]);
}

// ---------------------------------------------------------------- merged QKV GEMM
// A (4096 x 2048) bf16, Bt3 (6144 x 2048) bf16 = [Wq^T; Wk^T; Wv^T].
// 128x128 tile, BK=32, global_load_lds w16, XOR-chunk-swizzled LDS (conflict-free, verified R5).
// seg0/1 -> Q/K bf16 row-major; seg2 -> V transposed to (B,H,HD,S).
// Lean epilogue on purpose: fused norm (R4) cost VGPR 76->128, occ 31->21%, -28% perf.
__global__ __launch_bounds__(256) void gemm_qkv_kernel(const u16* __restrict__ A,
                                                       const u16* __restrict__ Bt3,
                                                       u16* __restrict__ Qb,
                                                       u16* __restrict__ Kb,
                                                       u16* __restrict__ Vtb) {
    constexpr int Kk = 2048;
    __shared__ u16 As[128 * 32];
    __shared__ u16 Bs[128 * 32];

    const int tid  = threadIdx.x;
    const int m0   = blockIdx.y * 128, n0 = blockIdx.x * 128;
    const int wid  = tid >> 6, lane = tid & 63;
    const int wm   = (wid >> 1) * 64, wn = (wid & 1) * 64;
    const int quad = lane >> 4, lrow = lane & 15;
    const int lr4  = lane >> 2, lc4 = lane & 3;
    const int swz  = (lr4 >> 1) & 3;           // staging-side swizzle
    const int rsw  = (lrow >> 1) & 3;          // read-side swizzle

    f32x4 acc[4][4];
#pragma unroll
    for (int a = 0; a < 4; ++a)
#pragma unroll
        for (int b = 0; b < 4; ++b) acc[a][b] = (f32x4)0.0f;

    for (int k0 = 0; k0 < Kk; k0 += 32) {
        __syncthreads();
#pragma unroll
        for (int it = 0; it < 2; ++it) {
            const int ra = (wid + 4 * it) * 16;
            async_ld16(&A  [(long)(m0 + ra + lr4) * Kk + k0 + ((lc4 ^ swz) * 8)], &As[ra * 32]);
            async_ld16(&Bt3[(long)(n0 + ra + lr4) * Kk + k0 + ((lc4 ^ swz) * 8)], &Bs[ra * 32]);
        }
        __syncthreads();

        short8 af[4], bf[4];
#pragma unroll
        for (int t = 0; t < 4; ++t)
            af[t] = *(const short8*)&As[(wm + t * 16 + lrow) * 32 + ((quad ^ rsw) * 8)];
#pragma unroll
        for (int t = 0; t < 4; ++t)
            bf[t] = *(const short8*)&Bs[(wn + t * 16 + lrow) * 32 + ((quad ^ rsw) * 8)];
#pragma unroll
        for (int tm = 0; tm < 4; ++tm)
#pragma unroll
            for (int tn = 0; tn < 4; ++tn)
                acc[tm][tn] = __builtin_amdgcn_mfma_f32_16x16x32_bf16(
                    af[tm], bf[tn], acc[tm][tn], 0, 0, 0);
    }

    const int seg = n0 >> 11;  // block-uniform: 0=Q, 1=K, 2=V
#pragma unroll
    for (int tm = 0; tm < 4; ++tm)
#pragma unroll
        for (int tn = 0; tn < 4; ++tn) {
            const int colg = (n0 & 2047) + wn + tn * 16 + lrow;
            const int rowb = m0 + wm + tm * 16 + quad * 4;
            if (seg == 2) {
                const int b = rowb >> 11, s = rowb & (S_ - 1);
                const int h = colg >> 7, d = colg & (HD_ - 1);
                ushort4 pk;
                pk.x = f2b(acc[tm][tn][0]); pk.y = f2b(acc[tm][tn][1]);
                pk.z = f2b(acc[tm][tn][2]); pk.w = f2b(acc[tm][tn][3]);
                *(ushort4*)&Vtb[((long)((b * H_ + h) * HD_ + d)) * S_ + s] = pk;
            } else {
                u16* dst = (seg == 0) ? Qb : Kb;
#pragma unroll
                for (int r = 0; r < 4; ++r)
                    dst[(long)(rowb + r) * N_ + colg] = f2b(acc[tm][tn][r]);
            }
        }
}

// ---------------------------------------------------------------- final projection GEMM (fp32 out), swizzled LDS
__global__ __launch_bounds__(256) void gemm_out_kernel(const u16* __restrict__ A,
                                                       const u16* __restrict__ Bt,
                                                       float* __restrict__ C) {
    constexpr int Kk = 2048, Nn = 2048;
    __shared__ u16 As[128 * 32];
    __shared__ u16 Bs[128 * 32];

    const int tid  = threadIdx.x;
    const int m0   = blockIdx.y * 128, n0 = blockIdx.x * 128;
    const int wid  = tid >> 6, lane = tid & 63;
    const int wm   = (wid >> 1) * 64, wn = (wid & 1) * 64;
    const int quad = lane >> 4, lrow = lane & 15;
    const int lr4  = lane >> 2, lc4 = lane & 3;
    const int swz  = (lr4 >> 1) & 3;
    const int rsw  = (lrow >> 1) & 3;

    f32x4 acc[4][4];
#pragma unroll
    for (int a = 0; a < 4; ++a)
#pragma unroll
        for (int b = 0; b < 4; ++b) acc[a][b] = (f32x4)0.0f;

    for (int k0 = 0; k0 < Kk; k0 += 32) {
        __syncthreads();
#pragma unroll
        for (int it = 0; it < 2; ++it) {
            const int ra = (wid + 4 * it) * 16;
            async_ld16(&A [(long)(m0 + ra + lr4) * Kk + k0 + ((lc4 ^ swz) * 8)], &As[ra * 32]);
            async_ld16(&Bt[(long)(n0 + ra + lr4) * Kk + k0 + ((lc4 ^ swz) * 8)], &Bs[ra * 32]);
        }
        __syncthreads();

        short8 af[4], bf[4];
#pragma unroll
        for (int t = 0; t < 4; ++t)
            af[t] = *(const short8*)&As[(wm + t * 16 + lrow) * 32 + ((quad ^ rsw) * 8)];
#pragma unroll
        for (int t = 0; t < 4; ++t)
            bf[t] = *(const short8*)&Bs[(wn + t * 16 + lrow) * 32 + ((quad ^ rsw) * 8)];
#pragma unroll
        for (int tm = 0; tm < 4; ++tm)
#pragma unroll
            for (int tn = 0; tn < 4; ++tn)
                acc[tm][tn] = __builtin_amdgcn_mfma_f32_16x16x32_bf16(
                    af[tm], bf[tn], acc[tm][tn], 0, 0, 0);
    }

#pragma unroll
    for (int tm = 0; tm < 4; ++tm)
#pragma unroll
        for (int tn = 0; tn < 4; ++tn) {
            const int col  = n0 + wn + tn * 16 + lrow;
            const int rowb = m0 + wm + tm * 16 + quad * 4;
#pragma unroll
            for (int r = 0; r < 4; ++r)
                C[(long)(rowb + r) * Nn + col] = acc[tm][tn][r];
        }
}

// ---------------------------------------------------------------- RMSNorm + RoPE, vectorized, in place
// One wave per row (x2 reps). Lane l holds d=2l,2l+1 (dword); rotate-half partner
// lives in lane l^32 -> shfl_xor(.,32). grid.y selects Q/K.
__global__ __launch_bounds__(256) void norm_rope_kernel(u16* __restrict__ Q, u16* __restrict__ Kb,
                                                        const float* __restrict__ qsc,
                                                        const float* __restrict__ ksc,
                                                        const float* __restrict__ cosp,
                                                        const float* __restrict__ sinp) {
    u16* X = blockIdx.y ? Kb : Q;
    const float* scale = blockIdx.y ? ksc : qsc;
    const int wid = threadIdx.x >> 6, lane = threadIdx.x & 63;
    const float2 sc2 = ((const float2*)scale)[lane];
    const float sgn = (lane < 32) ? -1.0f : 1.0f;
#pragma unroll
    for (int rep = 0; rep < 2; ++rep) {
        const int row = blockIdx.x * 8 + rep * 4 + wid;     // (b*S+s)*H + h
        const int s   = (row >> 4) & (S_ - 1);
        unsigned int v = ((const unsigned int*)X)[(long)row * 64 + lane];
        float x0 = b2f((u16)(v & 0xffff)), x1 = b2f((u16)(v >> 16));
        float ss = x0 * x0 + x1 * x1;
#pragma unroll
        for (int o = 1; o < 64; o <<= 1) ss += __shfl_xor(ss, o);
        const float inv = rsqrtf(ss * (1.0f / HD_) + 1e-6f);
        const float n0 = x0 * sc2.x * inv, n1 = x1 * sc2.y * inv;
        const float p0 = __shfl_xor(n0, 32), p1 = __shfl_xor(n1, 32);
        const float2 c2 = ((const float2*)(cosp + (long)s * HD_))[lane];
        const float2 s2 = ((const float2*)(sinp + (long)s * HD_))[lane];
        const float o0 = n0 * c2.x + sgn * p0 * s2.x;
        const float o1 = n1 * c2.y + sgn * p1 * s2.y;
        ((unsigned int*)X)[(long)row * 64 + lane] =
            ((unsigned int)f2b(o1) << 16) | (unsigned int)f2b(o0);
    }
}

// ---------------------------------------------------------------- MFMA flash attention
// Block: (b,h) x 128 queries; 8 waves x 16 q rows; 64-key tiles (proven best config, R5).
// Complementary qb pairing: co-resident blocks c and c+256 get qb with tiles summing
// ~const (R6 lesson: same-qb pairing maximizes the worst CU load).
// Fixed-shift softmax. K/V staged via global_load_lds with XOR chunk swizzle.
__global__ __launch_bounds__(512, 4) void fattn_kernel(const u16* __restrict__ Q,
                                                       const u16* __restrict__ K,
                                                       const u16* __restrict__ Vt,
                                                       u16* __restrict__ O) {
    __shared__ u16 Ks[64 * 128];      // [key][d-chunk swizzled], 256B rows
    __shared__ u16 Vs[128 * 64];      // [d][key-chunk swizzled], 128B rows
    __shared__ u16 Ps[8][16 * 72];    // per-wave [q][key], stride 144B (16B-aligned)

    const int tid  = threadIdx.x;
    const int wid  = tid >> 6, lane = tid & 63;
    const int quad = lane >> 4, lrow = lane & 15;
    const int i    = blockIdx.x & 15;
    const int pass = blockIdx.x >> 8;               // 0..1
    const int bh   = pass * 16 + ((blockIdx.x >> 4) & 15);
    const int qb   = pass ? i : 15 - i;             // heavy-first in pass0, complement in pass1
    const int h  = bh & (H_ - 1);
    const int b  = bh >> 4;
    const int q0  = qb * 128;
    const int q0w = q0 + wid * 16;

    // Q A-frags: lane holds Q[q=q0w+lrow][d = c*32 + quad*8 .. +7]
    short8 qf[4];
    const long qrow = ((long)(b * S_ + q0w + lrow) * H_ + h) * HD_;
#pragma unroll
    for (int c = 0; c < 4; ++c)
        qf[c] = *(const short8*)&Q[qrow + c * 32 + quad * 8];

    float l_r[4] = {0.f, 0.f, 0.f, 0.f};
    f32x4 oacc[8];
#pragma unroll
    for (int t = 0; t < 8; ++t) oacc[t] = (f32x4)0.0f;

    const int ktlo = (q0 - WIN_ > 0) ? (q0 - WIN_) : 0;   // 64-aligned
    const long kgbase = ((long)b * S_ * H_ + h) * HD_;
    const long vgbase = ((long)(b * H_ + h) * HD_) * S_;
    const int lxor = lrow & 7;

    for (int kt0 = ktlo; kt0 < q0 + 128; kt0 += 64) {
        __syncthreads();  // previous tile's LDS reads done
#pragma unroll
        for (int it = 0; it < 2; ++it) {
            const int rb = (wid * 2 + it) * 4;
            const int row = rb + (lane >> 4);
            const int cg = (lane & 15) ^ (row & 7);
            async_ld16(&K[kgbase + (long)(kt0 + row) * (H_ * HD_) + cg * 8], &Ks[rb * 128]);
        }
#pragma unroll
        for (int it = 0; it < 2; ++it) {
            const int db = (wid * 2 + it) * 8;
            const int d = db + (lane >> 3);
            const int cg = (lane & 7) ^ (d & 7);
            async_ld16(&Vt[vgbase + (long)d * S_ + kt0 + cg * 8], &Vs[db * 64]);
        }
        __syncthreads();  // drains vmcnt

        const bool active = (kt0 <= q0w + 15) && (kt0 + 63 >= q0w - WIN_);
        if (active) {
            f32x4 cs[4];
#pragma unroll
            for (int t = 0; t < 4; ++t) {
                cs[t] = (f32x4)0.0f;
                const int krow = (t * 16 + lrow) * 128;
#pragma unroll
                for (int c = 0; c < 4; ++c) {
                    short8 kf = *(const short8*)&Ks[krow + (((c * 4 + quad) ^ lxor) * 8)];
                    cs[t] = __builtin_amdgcn_mfma_f32_16x16x32_bf16(qf[c], kf, cs[t], 0, 0, 0);
                }
            }

            const bool full = (kt0 + 63 <= q0w) && (kt0 >= q0w + 15 - WIN_);
            if (!full) {
#pragma unroll
                for (int t = 0; t < 4; ++t) {
                    const int jc = kt0 + t * 16 + lrow;
#pragma unroll
                    for (int r = 0; r < 4; ++r) {
                        const int qi = q0w + quad * 4 + r;
                        if (jc > qi || jc < qi - WIN_) cs[t][r] = -1e30f;
                    }
                }
            }

#pragma unroll
            for (int t = 0; t < 4; ++t)
#pragma unroll
                for (int r = 0; r < 4; ++r) {
                    float p = __expf(fmaf(cs[t][r], SCALE_, -CSHIFT_));
                    l_r[r] += p;
                    Ps[wid][(quad * 4 + r) * 72 + t * 16 + lrow] = f2b(p);
                }

            short8 pf0 = *(const short8*)&Ps[wid][lrow * 72 + quad * 8];
            short8 pf1 = *(const short8*)&Ps[wid][lrow * 72 + 32 + quad * 8];
#pragma unroll
            for (int t = 0; t < 8; ++t) {
                const int vrow = (t * 16 + lrow) * 64;
                short8 vf0 = *(const short8*)&Vs[vrow + ((quad ^ lxor) * 8)];
                short8 vf1 = *(const short8*)&Vs[vrow + (((quad + 4) ^ lxor) * 8)];
                oacc[t] = __builtin_amdgcn_mfma_f32_16x16x32_bf16(pf0, vf0, oacc[t], 0, 0, 0);
                oacc[t] = __builtin_amdgcn_mfma_f32_16x16x32_bf16(pf1, vf1, oacc[t], 0, 0, 0);
            }
        }
    }

    float inv[4];
#pragma unroll
    for (int r = 0; r < 4; ++r) {
        float v = l_r[r];
#pragma unroll
        for (int o = 1; o < 16; o <<= 1) v += __shfl_xor(v, o);
        inv[r] = 1.0f / v;
    }

#pragma unroll
    for (int t = 0; t < 8; ++t) {
        const int d = t * 16 + lrow;
#pragma unroll
        for (int r = 0; r < 4; ++r) {
            const int q = q0w + quad * 4 + r;
            O[(long)(b * S_ + q) * N_ + h * HD_ + d] = f2b(oacc[t][r] * inv[r]);
        }
    }
}

// ----------------------------------------------------------------
extern "C" void kernel_launch(void* const* d_in, const int* in_sizes, int n_in,
                              void* d_out, int out_size, void* d_ws, size_t ws_size,
                              hipStream_t stream) {
    const float* hs   = (const float*)d_in[0];
    const float* cosp = (const float*)d_in[1];
    const float* sinp = (const float*)d_in[2];
    const float* Wq   = (const float*)d_in[3];
    const float* Wk   = (const float*)d_in[4];
    const float* Wv   = (const float*)d_in[5];
    const float* Wo   = (const float*)d_in[6];
    const float* qsc  = (const float*)d_in[7];
    const float* ksc  = (const float*)d_in[8];
    float* out = (float*)d_out;

    char* ws = (char*)d_ws;
    const size_t MD = (size_t)M_ * D_;  // 8M elems
    const size_t WN = (size_t)D_ * N_;  // 4M elems
    u16* hsb = (u16*)ws;                 // reused as attention output later
    u16* Wqt = (u16*)(ws + MD * 2);      // Wqt/Wkt/Wvt contiguous -> one 6144-row B
    u16* Wkt = Wqt + WN;
    u16* Wvt = Wkt + WN;
    u16* Wot = Wvt + WN;
    u16* Qb  = Wot + WN;
    u16* Kb  = Qb + MD;
    u16* Vtb = Kb + MD;                  // V transposed (B,H,HD,S)
    u16* Ab  = hsb;

    dim3 gp(64, 64, 5);
    prep_kernel<<<gp, 256, 0, stream>>>(hs, hsb, Wq, Wk, Wv, Wo, Wqt, Wkt, Wvt, Wot);

    dim3 gqkv(48, 32);  // N=6144
    gemm_qkv_kernel<<<gqkv, 256, 0, stream>>>(hsb, Wqt, Qb, Kb, Vtb);

    dim3 gn(B_ * S_ * H_ / 8, 2);
    norm_rope_kernel<<<gn, 256, 0, stream>>>(Qb, Kb, qsc, ksc, cosp, sinp);

    fattn_kernel<<<B_ * H_ * (S_ / 128), 512, 0, stream>>>(Qb, Kb, Vtb, Ab);

    dim3 gout(16, 32);
    gemm_out_kernel<<<gout, 256, 0, stream>>>(Ab, Wot, out);
}